// Round 1
// baseline (92.146 us; speedup 1.0000x reference)
//
#include <hip/hip_runtime.h>

#define N_NODES 30000
#define C 128
#define E_EDGES 480000
#define BLK_M 64
#define FS_STRIDE 132   // 128 + 4 pad; row stride bytes = 528 (16B aligned)

// ws layout (float units):
//   B[set]   : set*32768   .. (+128*256)   fused weight [k][j], j in 0..255
//   cv[set]  : 65536 + set*256
//   mask[g]  : 66048 + g*N_NODES   g: 0=graph1, 1=graph21, 2=graph2, 3=graph12
#define B_OFF(set)  ((set) * 32768)
#define CV_OFF(set) (65536 + (set) * 256)
#define MASK_OFF(g) (66048 + (g) * N_NODES)

// ---------------------------------------------------------------------------
// Prep: B[k][j] = sum_c wv[c][k] * wp[j&127][(j<128 ? c : 128+c)]
//       cv[j]   = sum_c bv[c]    * wp[j&127][(j<128 ? c : 128+c)]
// grid (128, 2), block 256
// ---------------------------------------------------------------------------
__global__ void prep_kernel(const float* __restrict__ wv1, const float* __restrict__ bv1,
                            const float* __restrict__ wp1,
                            const float* __restrict__ wv2, const float* __restrict__ bv2,
                            const float* __restrict__ wp2,
                            float* __restrict__ ws) {
  const int krow = blockIdx.x;
  const int set  = blockIdx.y;
  const float* wv = set ? wv2 : wv1;
  const float* bv = set ? bv2 : bv1;
  const float* wp = set ? wp2 : wp1;

  __shared__ float wvcol[C];
  const int t = threadIdx.x;
  if (t < C) wvcol[t] = wv[t * C + krow];   // column k of wv
  __syncthreads();

  const int j = t;  // 0..255
  const float* wprow = wp + (j & 127) * (2 * C) + ((j < C) ? 0 : C);
  float s = 0.f;
#pragma unroll 4
  for (int c = 0; c < C; ++c) s += wvcol[c] * wprow[c];
  ws[B_OFF(set) + krow * 256 + j] = s;

  if (krow == 0) {
    float s2 = 0.f;
#pragma unroll 4
    for (int c = 0; c < C; ++c) s2 += bv[c] * wprow[c];
    ws[CV_OFF(set) + j] = s2;
  }
}

// ---------------------------------------------------------------------------
// Masks
// ---------------------------------------------------------------------------
__global__ void zero_masks(float* __restrict__ ws) {
  const int idx = blockIdx.x * 256 + threadIdx.x;
  if (idx < 4 * N_NODES) ws[66048 + idx] = 0.f;
}

__global__ void scatter_masks(const int* __restrict__ g1, const int* __restrict__ g21,
                              const int* __restrict__ g2, const int* __restrict__ g12,
                              float* __restrict__ ws) {
  const int e = blockIdx.x * 256 + threadIdx.x;
  if (e >= E_EDGES) return;
  const int g = blockIdx.y;
  const int* gp = (g == 0) ? g1 : (g == 1) ? g21 : (g == 2) ? g2 : g12;
  ws[MASK_OFF(g) + gp[e]] = 1.0f;  // idempotent; races benign
}

// ---------------------------------------------------------------------------
// Main: per set, T = feat @ B  ([BLK_M x 256]); then
//   out[i][j] = hA[i]*(T[i][j]+cv[j]) + hB[i]*(T[i][j+128]+cv[j+128]) + bp[j]
// grid (ceil(N/BLK_M), 2), block 256. Thread tile 8 rows x 8 cols (cols strided 32).
// ---------------------------------------------------------------------------
__global__ __launch_bounds__(256) void main_kernel(
    const float* __restrict__ feat1, const float* __restrict__ feat2,
    const float* __restrict__ bp1, const float* __restrict__ bp2,
    const float* __restrict__ ws, float* __restrict__ out) {
  const int set = blockIdx.y;
  const float* feat = set ? feat2 : feat1;
  const float* bp   = set ? bp2 : bp1;
  const float* Bg   = ws + B_OFF(set);
  const float* cv   = ws + CV_OFF(set);
  const float* mA   = ws + MASK_OFF(2 * set);      // graph1 / graph2
  const float* mB   = ws + MASK_OFF(2 * set + 1);  // graph21 / graph12
  float* outp = out + (size_t)set * N_NODES * C;

  __shared__ float feat_s[BLK_M * FS_STRIDE];  // [r][k], 33792 B
  __shared__ float Bs[32 * 256];               // [k][j], 32768 B

  const int i0 = blockIdx.x * BLK_M;
  const int tid = threadIdx.x;

  // ---- stage feat tile: 64 rows x 32 float4 ----
#pragma unroll
  for (int l = 0; l < 8; ++l) {
    const int idx = tid + 256 * l;  // 0..2047
    const int r = idx >> 5;
    const int kq = idx & 31;
    float4 v = make_float4(0.f, 0.f, 0.f, 0.f);
    const int gi = i0 + r;
    if (gi < N_NODES) v = reinterpret_cast<const float4*>(feat + (size_t)gi * C)[kq];
    *reinterpret_cast<float4*>(&feat_s[r * FS_STRIDE + kq * 4]) = v;
  }

  const int ct = tid & 31;  // col base (j = ct + 32u)
  const int rt = tid >> 5;  // row tile 0..7

  float acc[8][8];
#pragma unroll
  for (int m = 0; m < 8; ++m)
#pragma unroll
    for (int u = 0; u < 8; ++u) acc[m][u] = 0.f;

  for (int kk = 0; kk < C; kk += 32) {
    __syncthreads();  // protect Bs from previous readers / ensure feat_s visible
    // stage B chunk [32][256]: 2048 float4
#pragma unroll
    for (int l = 0; l < 8; ++l) {
      const int idx = tid + 256 * l;
      const int k = idx >> 6;
      const int cq = idx & 63;
      float4 v = reinterpret_cast<const float4*>(Bg + (kk + k) * 256)[cq];
      *reinterpret_cast<float4*>(&Bs[k * 256 + cq * 4]) = v;
    }
    __syncthreads();

#pragma unroll 8
    for (int k = 0; k < 32; ++k) {
      float fr[8], br[8];
#pragma unroll
      for (int m = 0; m < 8; ++m) fr[m] = feat_s[(rt * 8 + m) * FS_STRIDE + kk + k];
#pragma unroll
      for (int u = 0; u < 8; ++u) br[u] = Bs[k * 256 + ct + 32 * u];
#pragma unroll
      for (int m = 0; m < 8; ++m)
#pragma unroll
        for (int u = 0; u < 8; ++u) acc[m][u] += fr[m] * br[u];
    }
  }

  // ---- epilogue ----
#pragma unroll
  for (int m = 0; m < 8; ++m) {
    const int i = i0 + rt * 8 + m;
    if (i >= N_NODES) continue;
    const float hA = mA[i];
    const float hB = mB[i];
#pragma unroll
    for (int u = 0; u < 4; ++u) {
      const int j = ct + 32 * u;
      const float val = hA * (acc[m][u] + cv[j]) + hB * (acc[m][u + 4] + cv[j + 128]) + bp[j];
      outp[(size_t)i * C + j] = val;
    }
  }
}

// ---------------------------------------------------------------------------
extern "C" void kernel_launch(void* const* d_in, const int* in_sizes, int n_in,
                              void* d_out, int out_size, void* d_ws, size_t ws_size,
                              hipStream_t stream) {
  const float* feat1 = (const float*)d_in[0];
  const float* feat2 = (const float*)d_in[2];
  const float* wv1 = (const float*)d_in[20];
  const float* bv1 = (const float*)d_in[21];
  const float* wv2 = (const float*)d_in[22];
  const float* bv2 = (const float*)d_in[23];
  const float* wp1 = (const float*)d_in[24];
  const float* bp1 = (const float*)d_in[25];
  const float* wp2 = (const float*)d_in[26];
  const float* bp2 = (const float*)d_in[27];
  const int* graph1  = (const int*)d_in[28];
  const int* graph2  = (const int*)d_in[29];
  const int* graph12 = (const int*)d_in[30];
  const int* graph21 = (const int*)d_in[31];

  float* ws = (float*)d_ws;
  float* out = (float*)d_out;

  // 1) fused weights
  prep_kernel<<<dim3(128, 2), 256, 0, stream>>>(wv1, bv1, wp1, wv2, bv2, wp2, ws);
  // 2) zero masks (4 * 30000 floats)
  zero_masks<<<dim3((4 * N_NODES + 255) / 256), 256, 0, stream>>>(ws);
  // 3) scatter membership (graph[0] = first E ints of each (2,E) array)
  scatter_masks<<<dim3((E_EDGES + 255) / 256, 4), 256, 0, stream>>>(graph1, graph21, graph2, graph12, ws);
  // 4) masked fused GEMM + epilogue
  main_kernel<<<dim3((N_NODES + BLK_M - 1) / BLK_M, 2), 256, 0, stream>>>(
      feat1, feat2, bp1, bp2, ws, out);
}

// Round 2
// 46.533 us; speedup vs baseline: 1.9802x; 1.9802x over previous
//
#include <hip/hip_runtime.h>
#include <hip/hip_bf16.h>

#define N_NODES 30000
#define C 128
#define E_EDGES 480000
#define BM 64

typedef __attribute__((ext_vector_type(8))) short bf16x8;
typedef __attribute__((ext_vector_type(4))) float f32x4;

// ws layout:
//   bytes [0, 131072)            : Bt bf16 [set][256 cols][128 k]  (set*65536 B)
//   float offset 32768 + set*256 : cv f32 [set][256]
//   float offset 33280 + g*N     : masks f32 [4][N]  g: 0=graph1,1=graph21,2=graph2,3=graph12
#define CV_OFF_F(set) (32768 + (set) * 256)
#define MASK_OFF_F(g) (33280 + (g) * N_NODES)

__device__ __forceinline__ unsigned short f2bf(float f) {
  union { float f; unsigned int u; } v; v.f = f;
  unsigned int r = v.u + 0x7FFF + ((v.u >> 16) & 1);  // RNE
  return (unsigned short)(r >> 16);
}

// ---------------------------------------------------------------------------
// prep: Bt[set][j][k] = sum_c wv[c][k] * wp[j&127][(j<128 ? c : 128+c)]  (bf16)
//       cv[set][j]    = sum_c bv[c]    * wp[j&127][(j<128 ? c : 128+c)]  (f32)
// grid (128, 2), block 256
// ---------------------------------------------------------------------------
__global__ void prep_kernel(const float* __restrict__ wv1, const float* __restrict__ bv1,
                            const float* __restrict__ wp1,
                            const float* __restrict__ wv2, const float* __restrict__ bv2,
                            const float* __restrict__ wp2,
                            float* __restrict__ ws) {
  const int k = blockIdx.x;   // 0..127
  const int set = blockIdx.y;
  const float* wv = set ? wv2 : wv1;
  const float* bv = set ? bv2 : bv1;
  const float* wp = set ? wp2 : wp1;

  __shared__ float wvcol[C];
  const int t = threadIdx.x;
  if (t < C) wvcol[t] = wv[t * C + k];
  __syncthreads();

  const int j = t;  // 0..255
  const float* wprow = wp + (j & 127) * (2 * C) + ((j < C) ? 0 : C);
  float s = 0.f;
#pragma unroll 4
  for (int c = 0; c < C; ++c) s += wvcol[c] * wprow[c];
  unsigned short* bt = (unsigned short*)ws;
  bt[set * 32768 + j * 128 + k] = f2bf(s);

  if (k == 0) {
    float s2 = 0.f;
#pragma unroll 4
    for (int c = 0; c < C; ++c) s2 += bv[c] * wprow[c];
    ws[CV_OFF_F(set) + j] = s2;
  }
}

// ---------------------------------------------------------------------------
__global__ void zero_masks(float* __restrict__ ws) {
  const int idx = blockIdx.x * 256 + threadIdx.x;
  if (idx < 4 * N_NODES) ws[33280 + idx] = 0.f;
}

__global__ void scatter_masks(const int* __restrict__ g1, const int* __restrict__ g21,
                              const int* __restrict__ g2, const int* __restrict__ g12,
                              float* __restrict__ ws) {
  const int e = blockIdx.x * 256 + threadIdx.x;
  if (e >= E_EDGES) return;
  const int g = blockIdx.y;
  const int* gp = (g == 0) ? g1 : (g == 1) ? g21 : (g == 2) ? g2 : g12;
  ws[MASK_OFF_F(g) + gp[e]] = 1.0f;  // idempotent
}

// ---------------------------------------------------------------------------
// main: per set, T = feat(bf16) @ Bt^T via MFMA; epilogue combines halves.
// grid (ceil(N/64), 2), block 512 (8 waves = 2M x 4J).
// LDS: feat_s [64][128] bf16 swizzled (16KB) + bt_s [256][128] bf16 swizzled (64KB)
// ---------------------------------------------------------------------------
__global__ __launch_bounds__(512, 4) void main_kernel(
    const float* __restrict__ feat1, const float* __restrict__ feat2,
    const float* __restrict__ bp1, const float* __restrict__ bp2,
    const float* __restrict__ ws, float* __restrict__ out) {
  const int set = blockIdx.y;
  const float* feat = set ? feat2 : feat1;
  const float* bp   = set ? bp2 : bp1;
  const unsigned short* Bt = (const unsigned short*)ws + (size_t)set * 32768;
  const float* cv = ws + CV_OFF_F(set);
  const float* mA = ws + MASK_OFF_F(2 * set);
  const float* mB = ws + MASK_OFF_F(2 * set + 1);
  float* outp = out + (size_t)set * N_NODES * C;

  __shared__ unsigned short feat_s[BM * 128];   // 16 KB
  __shared__ unsigned short bt_s[256 * 128];    // 64 KB

  const int i0 = blockIdx.x * BM;
  const int tid = threadIdx.x;

  // ---- stage feat tile: 64 rows x 128 cols, f32 -> bf16, swizzled ----
#pragma unroll
  for (int l = 0; l < 4; ++l) {
    const int idx = tid + 512 * l;       // 0..2047
    const int r = idx >> 5;              // row 0..63
    const int q = idx & 31;              // float4 group
    float4 v = make_float4(0.f, 0.f, 0.f, 0.f);
    if (i0 + r < N_NODES) v = reinterpret_cast<const float4*>(feat + (size_t)(i0 + r) * C)[q];
    ushort4 h;
    h.x = f2bf(v.x); h.y = f2bf(v.y); h.z = f2bf(v.z); h.w = f2bf(v.w);
    int byte = r * 256 + q * 8;
    byte ^= ((r & 7) << 4);
    *reinterpret_cast<ushort4*>(reinterpret_cast<char*>(feat_s) + byte) = h;
  }
  // ---- stage Bt: 256 cols x 128 k bf16 (64 KB), swizzled ----
#pragma unroll
  for (int l = 0; l < 8; ++l) {
    const int idx = tid + 512 * l;       // 0..4095
    const int cc = idx >> 4;             // col 0..255
    const int g = idx & 15;              // 16B chunk
    float4 v = reinterpret_cast<const float4*>(Bt + cc * 128)[g];
    int byte = cc * 256 + g * 16;
    byte ^= ((cc & 7) << 4);
    *reinterpret_cast<float4*>(reinterpret_cast<char*>(bt_s) + byte) = v;
  }
  __syncthreads();

  const int wave = tid >> 6;   // 0..7
  const int lane = tid & 63;
  const int wm = wave >> 2;    // 0..1 -> rows [wm*32, +32)
  const int wj = wave & 3;     // 0..3 -> jj   [wj*32, +32)
  const int l15 = lane & 15;
  const int lk  = lane >> 4;   // 0..3

  f32x4 acc[2][2][2] = {};     // [mt][nt][half]

#pragma unroll
  for (int ks = 0; ks < 4; ++ks) {
    bf16x8 a[2], b[2][2];
#pragma unroll
    for (int mt = 0; mt < 2; ++mt) {
      const int row = wm * 32 + mt * 16 + l15;
      int byte = row * 256 + ks * 64 + lk * 16;
      byte ^= ((row & 7) << 4);
      a[mt] = *reinterpret_cast<const bf16x8*>(reinterpret_cast<const char*>(feat_s) + byte);
    }
#pragma unroll
    for (int nt = 0; nt < 2; ++nt)
#pragma unroll
      for (int h = 0; h < 2; ++h) {
        const int col = wj * 32 + nt * 16 + h * 128 + l15;
        int byte = col * 256 + ks * 64 + lk * 16;
        byte ^= ((col & 7) << 4);
        b[nt][h] = *reinterpret_cast<const bf16x8*>(reinterpret_cast<const char*>(bt_s) + byte);
      }
#pragma unroll
    for (int mt = 0; mt < 2; ++mt)
#pragma unroll
      for (int nt = 0; nt < 2; ++nt)
#pragma unroll
        for (int h = 0; h < 2; ++h)
          acc[mt][nt][h] = __builtin_amdgcn_mfma_f32_16x16x32_bf16(
              a[mt], b[nt][h], acc[mt][nt][h], 0, 0, 0);
  }

  // ---- epilogue: out[i][jj] = hA*(TA+cv[jj]) + hB*(TB+cv[jj+128]) + bp[jj] ----
  float cvA[2], cvB[2], bpv[2];
#pragma unroll
  for (int nt = 0; nt < 2; ++nt) {
    const int jj = wj * 32 + nt * 16 + l15;
    cvA[nt] = cv[jj];
    cvB[nt] = cv[jj + 128];
    bpv[nt] = bp[jj];
  }
#pragma unroll
  for (int mt = 0; mt < 2; ++mt) {
#pragma unroll
    for (int r = 0; r < 4; ++r) {
      const int i = i0 + wm * 32 + mt * 16 + lk * 4 + r;
      if (i >= N_NODES) continue;
      const float hA = mA[i];
      const float hB = mB[i];
#pragma unroll
      for (int nt = 0; nt < 2; ++nt) {
        const int jj = wj * 32 + nt * 16 + l15;
        const float val = hA * (acc[mt][nt][0][r] + cvA[nt]) +
                          hB * (acc[mt][nt][1][r] + cvB[nt]) + bpv[nt];
        outp[(size_t)i * C + jj] = val;
      }
    }
  }
}

// ---------------------------------------------------------------------------
extern "C" void kernel_launch(void* const* d_in, const int* in_sizes, int n_in,
                              void* d_out, int out_size, void* d_ws, size_t ws_size,
                              hipStream_t stream) {
  const float* feat1 = (const float*)d_in[0];
  const float* feat2 = (const float*)d_in[2];
  const float* wv1 = (const float*)d_in[20];
  const float* bv1 = (const float*)d_in[21];
  const float* wv2 = (const float*)d_in[22];
  const float* bv2 = (const float*)d_in[23];
  const float* wp1 = (const float*)d_in[24];
  const float* bp1 = (const float*)d_in[25];
  const float* wp2 = (const float*)d_in[26];
  const float* bp2 = (const float*)d_in[27];
  const int* graph1  = (const int*)d_in[28];
  const int* graph2  = (const int*)d_in[29];
  const int* graph12 = (const int*)d_in[30];
  const int* graph21 = (const int*)d_in[31];

  float* ws = (float*)d_ws;
  float* out = (float*)d_out;

  prep_kernel<<<dim3(128, 2), 256, 0, stream>>>(wv1, bv1, wp1, wv2, bv2, wp2, ws);
  zero_masks<<<dim3((4 * N_NODES + 255) / 256), 256, 0, stream>>>(ws);
  scatter_masks<<<dim3((E_EDGES + 255) / 256, 4), 256, 0, stream>>>(graph1, graph21, graph2, graph12, ws);
  main_kernel<<<dim3((N_NODES + BM - 1) / BM, 2), 512, 0, stream>>>(
      feat1, feat2, bp1, bp2, ws, out);
}